// Round 5
// baseline (251.460 us; speedup 1.0000x reference)
//
#include <hip/hip_runtime.h>

// -------------------------------------------------------------------------
// GCN: h1 = relu(Agg(x@W1)+b1); h2 = relu(Agg(h1@W2)+b2); out = h2@Wl+bl
// R17 (from R16's 228.8us): agg L2-locality attack (R16 ablation showed
// aggs are gather-bound, not VALU-bound):
//   - t_bf / xh / xl re-laid out as 4 contiguous feature-quarter PLANES,
//     stride P=(N+1)*32 u16 (3.2MB/plane -> fits one XCD's 4MB L2;
//     contiguity keeps 128B lines within a plane).
//   - k_agg: block b -> quarter q=b&3, nodes=(b>>2)*8+wave*2+nh. With the
//     blockIdx%8 XCD round-robin, XCD x only touches plane x&3 -> gathers
//     L2-resident after first touch. 2 nodes/wave (8 edge groups x 4
//     feature lanes), 16 edges in flight, 3-step butterfly reduce.
//   - gemm3: A-read (!A32) and C-write (OUT_BF16) + zero row in plane
//     layout. x (fp32 input) and out (fp32) stay row-major.
// R16: v_pk_add_f32 accumulation (kept). R15/R14: swapped-operand MFMA
//   C^T epilogue (packed 8B stores); u16 edges; prepW fused into count;
//   dinv in scan1. Blo stays in LDS (R13: global B on MFMA path = -5us).
// Carried: bf16x3-split MFMA, XOR-swizzled LDS B, A prefetch, dinv
//   row-scaling fused in gemm, rank-capture CSR build, atomic-free place.
// Failed & reverted: grid barrier, node-XCD sharding (R9), fat-kernel
//   overlap, merged scan, Blo streaming (R13).
// -------------------------------------------------------------------------

typedef __attribute__((ext_vector_type(8))) __bf16 bf16x8;
typedef __attribute__((ext_vector_type(8))) short short8;
typedef __attribute__((ext_vector_type(4))) float f32x4;
typedef __attribute__((ext_vector_type(2))) float f32x2;

__device__ inline float bf_lo(unsigned u) { return __uint_as_float(u << 16); }
__device__ inline float bf_hi(unsigned u) { return __uint_as_float(u & 0xffff0000u); }
__device__ inline unsigned short f2bf(float v) {
  return __builtin_bit_cast(unsigned short, (__bf16)v);
}
// packed 2xf32 add (VOP3P)
__device__ inline f32x2 pkadd(f32x2 a, f32x2 b) {
  f32x2 d;
  asm("v_pk_add_f32 %0, %1, %2" : "=v"(d) : "v"(a), "v"(b));
  return d;
}
// bf16 pair word -> float2 {low half, high half}
__device__ inline f32x2 bfpair(unsigned w) {
  f32x2 r;
  r.x = __uint_as_float(w << 16);
  r.y = __uint_as_float(w & 0xffff0000u);
  return r;
}

// fat kernel: blocks [0, nbe) count in-degrees + capture rank;
// blocks [nbe, nbe+160) split/transpose weights to bf16 hi/lo
__global__ void k_count_prepW(const int* __restrict__ dst, int E, int nbe,
                              int* __restrict__ cnt, int* __restrict__ rank,
                              const float* __restrict__ W1, const float* __restrict__ W2,
                              const float* __restrict__ Wl,
                              unsigned short* __restrict__ b1h, unsigned short* __restrict__ b1l,
                              unsigned short* __restrict__ b2h, unsigned short* __restrict__ b2l,
                              unsigned short* __restrict__ blh, unsigned short* __restrict__ bll) {
  if ((int)blockIdx.x < nbe) {
    int i = blockIdx.x * 256 + threadIdx.x;
    if (i < E) rank[i] = atomicAdd(&cnt[dst[i]], 1);
  } else {
    int idx = ((int)blockIdx.x - nbe) * 256 + threadIdx.x;
    const float* W;
    unsigned short *bh, *bl_;
    int N, local;
    if (idx < 16384)      { W = W1; bh = b1h; bl_ = b1l; N = 128; local = idx; }
    else if (idx < 32768) { W = W2; bh = b2h; bl_ = b2l; N = 128; local = idx - 16384; }
    else if (idx < 40960) { W = Wl; bh = blh; bl_ = bll; N = 64;  local = idx - 32768; }
    else return;
    int nn = local >> 7, k = local & 127;
    float v = W[(size_t)k * N + nn];
    __bf16 h = (__bf16)v;
    bh[local] = __builtin_bit_cast(unsigned short, h);
    bl_[local] = f2bf(v - (float)h);
  }
}

// scan1: per-block partial sums of cnt; also dinv = rsqrt(deg+1)
__global__ void k_scan1(const int* __restrict__ cnt, int n, int* __restrict__ partial,
                        float* __restrict__ dinv) {
  __shared__ int s[256];
  int i = blockIdx.x * 256 + threadIdx.x;
  int v = (i < n) ? cnt[i] : 0;
  s[threadIdx.x] = v;
  if (i < n) dinv[i] = rsqrtf((float)(v + 1));
  __syncthreads();
  for (int off = 128; off > 0; off >>= 1) {
    if (threadIdx.x < off) s[threadIdx.x] += s[threadIdx.x + off];
    __syncthreads();
  }
  if (threadIdx.x == 0) partial[blockIdx.x] = s[0];
}

// scan3: block base from partials + exclusive scan -> row_off
__global__ void k_scan3(const int* __restrict__ cnt, const int* __restrict__ partial,
                        int nb, int n, int* __restrict__ row_off) {
  __shared__ int s[256];
  __shared__ int base_s;
  int t = threadIdx.x;
  s[t] = (t < nb && t < (int)blockIdx.x) ? partial[t] : 0;
  __syncthreads();
  for (int off = 128; off > 0; off >>= 1) {
    if (t < off) s[t] += s[t + off];
    __syncthreads();
  }
  if (t == 0) base_s = s[0];
  __syncthreads();
  int base = base_s;
  __syncthreads();

  int i = blockIdx.x * 256 + t;
  int v = (i < n) ? cnt[i] : 0;
  s[t] = v;
  __syncthreads();
  for (int off = 1; off < 256; off <<= 1) {
    int u = (t >= off) ? s[t - off] : 0;
    __syncthreads();
    s[t] += u;
    __syncthreads();
  }
  int incl = s[t];
  int excl = incl - v;
  if (i < n) {
    row_off[i] = base + excl;
    if (i == n - 1) row_off[n] = base + incl;
  }
}

// place: NO atomics -- pos = row_off[dst] + rank; edges stored as u16
__global__ void k_place(const int* __restrict__ src, const int* __restrict__ dst,
                        const int* __restrict__ rank, const int* __restrict__ row_off,
                        int E, unsigned short* __restrict__ edges) {
  int e = blockIdx.x * blockDim.x + threadIdx.x;
  if (e < E) {
    int d = dst[e];
    int pos = row_off[d] + rank[e];
    __builtin_nontemporal_store((unsigned short)src[e], &edges[pos]);
  }
}

// ------------------- MFMA GEMM: A prefetched, B (hi+lo) in LDS -----------
// C[M x N] = A[M x 128] @ B[128 x N], N = NT*16.
// Operand-SWAPPED mfma: acc = mfma(b_frag, a_frag, acc) computes C^T tile
// layout: per lane, C-row = m_base+mt*16+lm, C-cols = nt*16+lk*4+r (r=0..3)
// -> packed 8B/16B epilogue stores.
// PLANES: when !A32, A is read from 4 feature-quarter planes (stride P);
// when OUT_BF16, C is written to planes. SCALE: row-scale by dinv + zero
// row M (agg OOB target) per plane.
template <int NT, bool A32, bool BIAS, bool OUT_BF16, bool SCALE>
__global__ __launch_bounds__(256) void gemm3(
    const void* __restrict__ Ahi_, const unsigned short* __restrict__ Alo,
    const unsigned short* __restrict__ Bhi, const unsigned short* __restrict__ Blo,
    const float* __restrict__ bias, const float* __restrict__ dinv,
    void* __restrict__ Cout, int M) {
  constexpr int K = 128;
  constexpr int NCOL = NT * 16;
  __shared__ alignas(16) unsigned short lbh[NCOL * K];
  __shared__ alignas(16) unsigned short lbl[NCOL * K];
  const size_t P = (size_t)(M + 1) * 32;   // plane stride (u16 elements)
  int t = threadIdx.x;
  int lane = t & 63, wave = t >> 6;
  int lm = lane & 15, lk = lane >> 4;
  int m_base = blockIdx.x * 128 + wave * 32;
  const short8 zero8 = {0, 0, 0, 0, 0, 0, 0, 0};

  if (SCALE && blockIdx.x == 0 && t < 64) {   // zero row M (all 4 planes)
    *(unsigned*)&((unsigned short*)Cout)[(size_t)(t >> 4) * P + (size_t)M * 32 + (t & 15) * 2] = 0u;
  }

  // ---- phase 1: prefetch all A fragments ----
  bf16x8 ah[2][4], al[2][4];
  if (A32) {
    const float* Af = (const float*)Ahi_;
    float4 ra[2][4][2];
#pragma unroll
    for (int mt = 0; mt < 2; ++mt) {
      int row = m_base + mt * 16 + lm;
#pragma unroll
      for (int ks = 0; ks < 4; ++ks) {
        if (row < M) {
          ra[mt][ks][0] = *(const float4*)&Af[(size_t)row * K + ks * 32 + lk * 8];
          ra[mt][ks][1] = *(const float4*)&Af[(size_t)row * K + ks * 32 + lk * 8 + 4];
        } else {
          ra[mt][ks][0] = make_float4(0.f, 0.f, 0.f, 0.f);
          ra[mt][ks][1] = make_float4(0.f, 0.f, 0.f, 0.f);
        }
      }
    }
#pragma unroll
    for (int mt = 0; mt < 2; ++mt)
#pragma unroll
      for (int ks = 0; ks < 4; ++ks) {
        float av[8] = {ra[mt][ks][0].x, ra[mt][ks][0].y, ra[mt][ks][0].z, ra[mt][ks][0].w,
                       ra[mt][ks][1].x, ra[mt][ks][1].y, ra[mt][ks][1].z, ra[mt][ks][1].w};
#pragma unroll
        for (int j = 0; j < 8; ++j) {
          __bf16 h = (__bf16)av[j];
          ah[mt][ks][j] = h;
          al[mt][ks][j] = (__bf16)(av[j] - (float)h);
        }
      }
  } else {
    const unsigned short* Ahi = (const unsigned short*)Ahi_;
#pragma unroll
    for (int mt = 0; mt < 2; ++mt) {
      int row = m_base + mt * 16 + lm;
#pragma unroll
      for (int ks = 0; ks < 4; ++ks) {
        if (row < M) {
          ah[mt][ks] = *(const bf16x8*)&Ahi[(size_t)ks * P + (size_t)row * 32 + lk * 8];
          al[mt][ks] = *(const bf16x8*)&Alo[(size_t)ks * P + (size_t)row * 32 + lk * 8];
        } else {
          ah[mt][ks] = __builtin_bit_cast(bf16x8, zero8);
          al[mt][ks] = __builtin_bit_cast(bf16x8, zero8);
        }
      }
    }
  }

  // ---- phase 2: cooperative B staging (XOR-swizzled 16B chunks) ----
  for (int c = t; c < NCOL * 16; c += 256) {
    int r = c >> 4, q = c & 15;
    int sq = q ^ (r & 15);
    *(short8*)&lbh[r * K + sq * 8] = *(const short8*)&Bhi[r * K + q * 8];
    *(short8*)&lbl[r * K + sq * 8] = *(const short8*)&Blo[r * K + q * 8];
  }
  __syncthreads();

  // ---- phase 3: pure LDS + MFMA, swapped operands ----
  f32x4 acc[2][NT] = {};
#pragma unroll
  for (int ks = 0; ks < 4; ++ks) {
    int chunk = ks * 4 + lk;
    bf16x8 bh[NT], bl[NT];
#pragma unroll
    for (int nt = 0; nt < NT; ++nt) {
      int r = nt * 16 + lm;
      int sq = chunk ^ lm;
      bh[nt] = *(const bf16x8*)&lbh[r * K + sq * 8];
      bl[nt] = *(const bf16x8*)&lbl[r * K + sq * 8];
    }
#pragma unroll
    for (int mt = 0; mt < 2; ++mt)
#pragma unroll
      for (int nt = 0; nt < NT; ++nt) {
        acc[mt][nt] = __builtin_amdgcn_mfma_f32_16x16x32_bf16(bh[nt], ah[mt][ks], acc[mt][nt], 0, 0, 0);
        acc[mt][nt] = __builtin_amdgcn_mfma_f32_16x16x32_bf16(bl[nt], ah[mt][ks], acc[mt][nt], 0, 0, 0);
        acc[mt][nt] = __builtin_amdgcn_mfma_f32_16x16x32_bf16(bh[nt], al[mt][ks], acc[mt][nt], 0, 0, 0);
      }
  }

  // ---- epilogue (transposed acc): row = m_base+mt*16+lm, cols = nt*16+lk*4+r
#pragma unroll
  for (int mt = 0; mt < 2; ++mt) {
    int row = m_base + mt * 16 + lm;
    if (row < M) {
      float dr = SCALE ? dinv[row] : 1.f;
#pragma unroll
      for (int nt = 0; nt < NT; ++nt) {
        int col0 = nt * 16 + lk * 4;
        float v0 = acc[mt][nt][0], v1 = acc[mt][nt][1];
        float v2 = acc[mt][nt][2], v3 = acc[mt][nt][3];
        if (SCALE) { v0 *= dr; v1 *= dr; v2 *= dr; v3 *= dr; }
        if (BIAS) {
          float4 bb = *(const float4*)&bias[col0];
          v0 += bb.x; v1 += bb.y; v2 += bb.z; v3 += bb.w;
        }
        if (OUT_BF16) {
          unsigned p0 = (unsigned)f2bf(v0) | ((unsigned)f2bf(v1) << 16);
          unsigned p1 = (unsigned)f2bf(v2) | ((unsigned)f2bf(v3) << 16);
          uint2 pk = make_uint2(p0, p1);
          *(uint2*)&((unsigned short*)Cout)[(size_t)(col0 >> 5) * P + (size_t)row * 32 + (col0 & 31)] = pk;
        } else {
          float4 pk = make_float4(v0, v1, v2, v3);
          *(float4*)&((float*)Cout)[(size_t)row * NCOL + col0] = pk;
        }
      }
    }
  }
}

// ------------------- aggregation: quarter-plane, XCD-pinned --------------
// block b: quarter q=b&3 (with %8 round-robin, XCD x only sees plane x&3,
// 3.2MB -> L2-resident), nodes=(b>>2)*8 + wave*2 + nh.
// Per node: 32 lanes = 8 edge groups x 4 feature lanes (16B each);
// 16 edges in flight; 3-step butterfly (xor 4,8,16) within node half.
// rows pre-scaled by dinv[src]; agg_i = dinv_i*(sum + self) + bias, relu.
__global__ __launch_bounds__(256) void k_agg(const unsigned short* __restrict__ t,
                      const int* __restrict__ row_off,
                      const unsigned short* __restrict__ edges,
                      const float* __restrict__ dinv, const float* __restrict__ bias,
                      unsigned short* __restrict__ ghi, unsigned short* __restrict__ glo,
                      int n) {
  const size_t P = (size_t)(n + 1) * 32;
  int q = blockIdx.x & 3;
  int wave = threadIdx.x >> 6;
  int lane = threadIdx.x & 63;
  int nh = lane >> 5;           // node half within wave
  int r = lane & 31;
  int g = r >> 2;               // 8 edge groups
  int fl = r & 3;               // 16B feature chunk within quarter
  int node = (blockIdx.x >> 2) * 8 + wave * 2 + nh;
  if (node >= n) return;
  int2 ro = *(const int2*)&row_off[node];
  int e0 = ro.x, e1 = ro.y;
  int last = e1 - 1;

  const unsigned short* tq = t + (size_t)q * P;
  // hoisted epilogue loads: overlap with gather chain
  float di = dinv[node];
  uint4 sv = *(const uint4*)&tq[(size_t)node * 32 + fl * 8];
  float4 bb0 = *(const float4*)&bias[q * 32 + fl * 8];
  float4 bb1 = *(const float4*)&bias[q * 32 + fl * 8 + 4];

  f32x2 acc2[4] = {};
  for (int base = e0; base < e1; base += 16) {
    int i0 = base + g, i1 = base + 8 + g;
    int s0 = edges[i0 < e1 ? i0 : last];
    int s1 = edges[i1 < e1 ? i1 : last];
    s0 = i0 < e1 ? s0 : n;     // zero row
    s1 = i1 < e1 ? s1 : n;
    uint4 u0 = *(const uint4*)&tq[(size_t)s0 * 32 + fl * 8];
    uint4 u1 = *(const uint4*)&tq[(size_t)s1 * 32 + fl * 8];
    acc2[0] = pkadd(acc2[0], pkadd(bfpair(u0.x), bfpair(u1.x)));
    acc2[1] = pkadd(acc2[1], pkadd(bfpair(u0.y), bfpair(u1.y)));
    acc2[2] = pkadd(acc2[2], pkadd(bfpair(u0.z), bfpair(u1.z)));
    acc2[3] = pkadd(acc2[3], pkadd(bfpair(u0.w), bfpair(u1.w)));
  }
  float acc[8];
#pragma unroll
  for (int j = 0; j < 4; ++j) { acc[2 * j] = acc2[j].x; acc[2 * j + 1] = acc2[j].y; }
#pragma unroll
  for (int j = 0; j < 8; ++j) {
    acc[j] += __shfl_xor(acc[j], 4);
    acc[j] += __shfl_xor(acc[j], 8);
    acc[j] += __shfl_xor(acc[j], 16);
  }
  if (g == 0) {
    acc[0] += bf_lo(sv.x); acc[1] += bf_hi(sv.x);
    acc[2] += bf_lo(sv.y); acc[3] += bf_hi(sv.y);
    acc[4] += bf_lo(sv.z); acc[5] += bf_hi(sv.z);
    acc[6] += bf_lo(sv.w); acc[7] += bf_hi(sv.w);
    float bb[8] = {bb0.x, bb0.y, bb0.z, bb0.w, bb1.x, bb1.y, bb1.z, bb1.w};
    short8 ho, lo_;
#pragma unroll
    for (int j = 0; j < 8; ++j) {
      float s = fmaxf(acc[j] * di + bb[j], 0.f);
      __bf16 h = (__bf16)s;
      ho[j] = __builtin_bit_cast(short, h);
      lo_[j] = (short)f2bf(s - (float)h);
    }
    *(short8*)&ghi[(size_t)q * P + (size_t)node * 32 + fl * 8] = ho;
    *(short8*)&glo[(size_t)q * P + (size_t)node * 32 + fl * 8] = lo_;
  }
}

extern "C" void kernel_launch(void* const* d_in, const int* in_sizes, int n_in,
                              void* d_out, int out_size, void* d_ws, size_t ws_size,
                              hipStream_t stream) {
  const float* x  = (const float*)d_in[0];
  const int*   ei = (const int*)d_in[1];
  const float* W1 = (const float*)d_in[2];
  const float* b1 = (const float*)d_in[3];
  const float* W2 = (const float*)d_in[4];
  const float* b2 = (const float*)d_in[5];
  const float* Wl = (const float*)d_in[6];
  const float* bl = (const float*)d_in[7];
  float* out = (float*)d_out;

  const int D = 128;
  int N = in_sizes[0] / D;
  int E = in_sizes[1] / 2;
  const int* src = ei;
  const int* dst = ei + E;

  uintptr_t ws = (uintptr_t)d_ws;
  auto take = [&](size_t bytes) {
    uintptr_t p = ws;
    ws += (bytes + 15) & ~(size_t)15;
    return p;
  };
  // plane-layout buffers: 4 planes x (N+1) rows x 32 u16
  unsigned short* t_bf = (unsigned short*)take(((size_t)N + 1) * D * 2);
  unsigned short* xh   = (unsigned short*)take(((size_t)N + 1) * D * 2);
  unsigned short* xl   = (unsigned short*)take(((size_t)N + 1) * D * 2);
  unsigned short* edges = (unsigned short*)take((size_t)E * 2);  // u16 src ids
  int*   rank    = (int*)take((size_t)E * 4);
  int*   cnt     = (int*)take((size_t)N * sizeof(int));
  int*   row_off = (int*)take(((size_t)N + 1) * sizeof(int));
  float* dinv    = (float*)take((size_t)N * sizeof(float));
  int*   partial = (int*)take(256 * sizeof(int));
  unsigned short* b1h = (unsigned short*)take(128 * 128 * 2);
  unsigned short* b1l = (unsigned short*)take(128 * 128 * 2);
  unsigned short* b2h = (unsigned short*)take(128 * 128 * 2);
  unsigned short* b2l = (unsigned short*)take(128 * 128 * 2);
  unsigned short* blh = (unsigned short*)take(128 * 64 * 2);
  unsigned short* bll = (unsigned short*)take(128 * 64 * 2);

  int nb_n = (N + 255) / 256;   // 196 (fits single-block base reduce)
  int nb_e = (E + 255) / 256;

  // ---- graph preprocessing + weight prep ----
  hipMemsetAsync(cnt, 0, (size_t)N * sizeof(int), stream);
  k_count_prepW<<<nb_e + 160, 256, 0, stream>>>(dst, E, nb_e, cnt, rank,
                                                W1, W2, Wl, b1h, b1l, b2h, b2l, blh, bll);
  k_scan1<<<nb_n, 256, 0, stream>>>(cnt, N, partial, dinv);
  k_scan3<<<nb_n, 256, 0, stream>>>(cnt, partial, nb_n, N, row_off);
  k_place<<<nb_e, 256, 0, stream>>>(src, dst, rank, row_off, E, edges);

  int gemm_blocks = (N + 127) / 128;
  int agg_blocks = 4 * ((N + 7) / 8);   // 25000 = 8*3125: clean %8 round-robin

  // ---- layer 1 (A = fp32 x, split in-register; output pre-scaled by dinv) ----
  gemm3<8, true, false, true, true><<<gemm_blocks, 256, 0, stream>>>(
      x, nullptr, b1h, b1l, nullptr, dinv, t_bf, N);
  k_agg<<<agg_blocks, 256, 0, stream>>>(t_bf, row_off, edges, dinv, b1, xh, xl, N);
  // ---- layer 2 ----
  gemm3<8, false, false, true, true><<<gemm_blocks, 256, 0, stream>>>(
      xh, xl, b2h, b2l, nullptr, dinv, t_bf, N);
  k_agg<<<agg_blocks, 256, 0, stream>>>(t_bf, row_off, edges, dinv, b2, xh, xl, N);
  // ---- classifier ----
  gemm3<4, false, true, false, false><<<gemm_blocks, 256, 0, stream>>>(
      xh, xl, blh, bll, bl, nullptr, out, N);
}

// Round 6
// 232.228 us; speedup vs baseline: 1.0828x; 1.0828x over previous
//
#include <hip/hip_runtime.h>

// -------------------------------------------------------------------------
// GCN: h1 = relu(Agg(x@W1)+b1); h2 = relu(Agg(h1@W2)+b2); out = h2@Wl+bl
// R18 (post-mortem R17: quarter-plane agg regressed 228.8->251.5 by 4x-ing
// per-node fixed costs; BUT it exposed k_agg counters: VALUBusy ~70%, HBM
// 14%, FETCH 24MB -> agg is VALU/issue-bound, gathers are cache-absorbed).
// Revert to R16 structure + strip VALU from agg (bit-identical numerics):
//   - PADDED CSR: rows padded to multiple of 16 edges, pad slots pre-filled
//     with zero-row index n (uint4 bulk fill fused into count_prepW;
//     k_place overwrites real slots; scans build padded row_off).
//     -> agg inner loop is BRANCHLESS: no cmp/cndmask clamp chains (~12
//     VALU/lane/iter removed, all on the gather address dep chain).
//   - agg writes fp32 (xf) instead of bf16 hi/lo pair (same bytes);
//     gemm2/classifier use the existing A32 split-in-register path.
//     Removes ~30 VALU of f2bf packing from agg epilogue; split math
//     identical on exact stored fp32 -> bit-identical outputs.
// R16: v_pk_add_f32 accumulation (kept). R15/R14: swapped-operand MFMA
//   C^T epilogue (packed stores); u16 edges; prepW fused into count; dinv
//   in scan1. Blo stays in LDS (R13: global B on MFMA path = -5us).
// Carried: bf16x3-split MFMA, XOR-swizzled LDS B, A prefetch, dinv
//   row-scaling fused in gemm, rank-capture CSR build, atomic-free place.
// Failed & reverted: grid barrier, node/feature XCD sharding (R9/R17),
//   fat-kernel overlap, merged scan, Blo streaming (R13).
// -------------------------------------------------------------------------

typedef __attribute__((ext_vector_type(8))) __bf16 bf16x8;
typedef __attribute__((ext_vector_type(8))) short short8;
typedef __attribute__((ext_vector_type(4))) float f32x4;
typedef __attribute__((ext_vector_type(2))) float f32x2;

__device__ inline float bf_lo(unsigned u) { return __uint_as_float(u << 16); }
__device__ inline float bf_hi(unsigned u) { return __uint_as_float(u & 0xffff0000u); }
__device__ inline unsigned short f2bf(float v) {
  return __builtin_bit_cast(unsigned short, (__bf16)v);
}
// packed 2xf32 add (VOP3P)
__device__ inline f32x2 pkadd(f32x2 a, f32x2 b) {
  f32x2 d;
  asm("v_pk_add_f32 %0, %1, %2" : "=v"(d) : "v"(a), "v"(b));
  return d;
}
// bf16 pair word -> float2 {low half, high half}
__device__ inline f32x2 bfpair(unsigned w) {
  f32x2 r;
  r.x = __uint_as_float(w << 16);
  r.y = __uint_as_float(w & 0xffff0000u);
  return r;
}

// fat kernel: [0,nbe) count in-degrees + capture rank; [nbe,nbe+160) prepW;
// [nbe+160, nbe+160+64) fill padded edges buffer with zero-row index n
__global__ void k_count_prepW(const int* __restrict__ dst, int E, int nbe, int n,
                              int* __restrict__ cnt, int* __restrict__ rank,
                              unsigned short* __restrict__ edges, int fill_q,
                              const float* __restrict__ W1, const float* __restrict__ W2,
                              const float* __restrict__ Wl,
                              unsigned short* __restrict__ b1h, unsigned short* __restrict__ b1l,
                              unsigned short* __restrict__ b2h, unsigned short* __restrict__ b2l,
                              unsigned short* __restrict__ blh, unsigned short* __restrict__ bll) {
  if ((int)blockIdx.x < nbe) {
    int i = blockIdx.x * 256 + threadIdx.x;
    if (i < E) rank[i] = atomicAdd(&cnt[dst[i]], 1);
  } else if ((int)blockIdx.x < nbe + 160) {
    int idx = ((int)blockIdx.x - nbe) * 256 + threadIdx.x;
    const float* W;
    unsigned short *bh, *bl_;
    int N, local;
    if (idx < 16384)      { W = W1; bh = b1h; bl_ = b1l; N = 128; local = idx; }
    else if (idx < 32768) { W = W2; bh = b2h; bl_ = b2l; N = 128; local = idx - 16384; }
    else if (idx < 40960) { W = Wl; bh = blh; bl_ = bll; N = 64;  local = idx - 32768; }
    else return;
    int nn = local >> 7, k = local & 127;
    float v = W[(size_t)k * N + nn];
    __bf16 h = (__bf16)v;
    bh[local] = __builtin_bit_cast(unsigned short, h);
    bl_[local] = f2bf(v - (float)h);
  } else {
    int b = (int)blockIdx.x - nbe - 160;
    unsigned w = ((unsigned)n << 16) | (unsigned)n;
    uint4 val = make_uint4(w, w, w, w);
    for (int i = b * 256 + threadIdx.x; i < fill_q; i += 64 * 256)
      ((uint4*)edges)[i] = val;
  }
}

// scan1: per-block partial sums of PADDED counts; dinv = rsqrt(deg+1)
__global__ void k_scan1(const int* __restrict__ cnt, int n, int* __restrict__ partial,
                        float* __restrict__ dinv) {
  __shared__ int s[256];
  int i = blockIdx.x * 256 + threadIdx.x;
  int v = (i < n) ? cnt[i] : 0;
  s[threadIdx.x] = (v + 15) & ~15;
  if (i < n) dinv[i] = rsqrtf((float)(v + 1));
  __syncthreads();
  for (int off = 128; off > 0; off >>= 1) {
    if (threadIdx.x < off) s[threadIdx.x] += s[threadIdx.x + off];
    __syncthreads();
  }
  if (threadIdx.x == 0) partial[blockIdx.x] = s[0];
}

// scan3: block base from partials + exclusive scan of PADDED counts -> row_off
__global__ void k_scan3(const int* __restrict__ cnt, const int* __restrict__ partial,
                        int nb, int n, int* __restrict__ row_off) {
  __shared__ int s[256];
  __shared__ int base_s;
  int t = threadIdx.x;
  s[t] = (t < nb && t < (int)blockIdx.x) ? partial[t] : 0;
  __syncthreads();
  for (int off = 128; off > 0; off >>= 1) {
    if (t < off) s[t] += s[t + off];
    __syncthreads();
  }
  if (t == 0) base_s = s[0];
  __syncthreads();
  int base = base_s;
  __syncthreads();

  int i = blockIdx.x * 256 + t;
  int v = (i < n) ? ((cnt[i] + 15) & ~15) : 0;
  s[t] = v;
  __syncthreads();
  for (int off = 1; off < 256; off <<= 1) {
    int u = (t >= off) ? s[t - off] : 0;
    __syncthreads();
    s[t] += u;
    __syncthreads();
  }
  int incl = s[t];
  int excl = incl - v;
  if (i < n) {
    row_off[i] = base + excl;
    if (i == n - 1) row_off[n] = base + incl;
  }
}

// place: NO atomics -- pos = row_off[dst] + rank; edges stored as u16.
// Pad slots keep their pre-filled zero-row index n.
__global__ void k_place(const int* __restrict__ src, const int* __restrict__ dst,
                        const int* __restrict__ rank, const int* __restrict__ row_off,
                        int E, unsigned short* __restrict__ edges) {
  int e = blockIdx.x * blockDim.x + threadIdx.x;
  if (e < E) {
    int d = dst[e];
    int pos = row_off[d] + rank[e];
    __builtin_nontemporal_store((unsigned short)src[e], &edges[pos]);
  }
}

// ------------------- MFMA GEMM: A prefetched, B (hi+lo) in LDS -----------
// C[M x N] = A[M x 128] @ B[128 x N], N = NT*16.
// Operand-SWAPPED mfma: acc = mfma(b_frag, a_frag, acc) computes C^T tile
// layout: per lane, C-row = m_base+mt*16+lm, C-cols = nt*16+lk*4+r (r=0..3)
// -> packed 8B/16B epilogue stores.
// SCALE: multiply output row r by dinv[r] and write zero row M (agg OOB).
template <int NT, bool A32, bool BIAS, bool OUT_BF16, bool SCALE>
__global__ __launch_bounds__(256) void gemm3(
    const void* __restrict__ Ahi_, const unsigned short* __restrict__ Alo,
    const unsigned short* __restrict__ Bhi, const unsigned short* __restrict__ Blo,
    const float* __restrict__ bias, const float* __restrict__ dinv,
    void* __restrict__ Cout, int M) {
  constexpr int K = 128;
  constexpr int NCOL = NT * 16;
  __shared__ alignas(16) unsigned short lbh[NCOL * K];
  __shared__ alignas(16) unsigned short lbl[NCOL * K];
  int t = threadIdx.x;
  int lane = t & 63, wave = t >> 6;
  int lm = lane & 15, lk = lane >> 4;
  int m_base = blockIdx.x * 128 + wave * 32;
  const short8 zero8 = {0, 0, 0, 0, 0, 0, 0, 0};

  if (SCALE && blockIdx.x == 0 && t < 64) {   // zero row M for agg OOB lanes
    *(unsigned*)&((unsigned short*)Cout)[(size_t)M * NCOL + t * 2] = 0u;
  }

  // ---- phase 1: prefetch all A fragments ----
  bf16x8 ah[2][4], al[2][4];
  if (A32) {
    const float* Af = (const float*)Ahi_;
    float4 ra[2][4][2];
#pragma unroll
    for (int mt = 0; mt < 2; ++mt) {
      int row = m_base + mt * 16 + lm;
#pragma unroll
      for (int ks = 0; ks < 4; ++ks) {
        if (row < M) {
          ra[mt][ks][0] = *(const float4*)&Af[(size_t)row * K + ks * 32 + lk * 8];
          ra[mt][ks][1] = *(const float4*)&Af[(size_t)row * K + ks * 32 + lk * 8 + 4];
        } else {
          ra[mt][ks][0] = make_float4(0.f, 0.f, 0.f, 0.f);
          ra[mt][ks][1] = make_float4(0.f, 0.f, 0.f, 0.f);
        }
      }
    }
#pragma unroll
    for (int mt = 0; mt < 2; ++mt)
#pragma unroll
      for (int ks = 0; ks < 4; ++ks) {
        float av[8] = {ra[mt][ks][0].x, ra[mt][ks][0].y, ra[mt][ks][0].z, ra[mt][ks][0].w,
                       ra[mt][ks][1].x, ra[mt][ks][1].y, ra[mt][ks][1].z, ra[mt][ks][1].w};
#pragma unroll
        for (int j = 0; j < 8; ++j) {
          __bf16 h = (__bf16)av[j];
          ah[mt][ks][j] = h;
          al[mt][ks][j] = (__bf16)(av[j] - (float)h);
        }
      }
  } else {
    const unsigned short* Ahi = (const unsigned short*)Ahi_;
#pragma unroll
    for (int mt = 0; mt < 2; ++mt) {
      int row = m_base + mt * 16 + lm;
#pragma unroll
      for (int ks = 0; ks < 4; ++ks) {
        if (row < M) {
          ah[mt][ks] = *(const bf16x8*)&Ahi[(size_t)row * K + ks * 32 + lk * 8];
          al[mt][ks] = *(const bf16x8*)&Alo[(size_t)row * K + ks * 32 + lk * 8];
        } else {
          ah[mt][ks] = __builtin_bit_cast(bf16x8, zero8);
          al[mt][ks] = __builtin_bit_cast(bf16x8, zero8);
        }
      }
    }
  }

  // ---- phase 2: cooperative B staging (XOR-swizzled 16B chunks) ----
  for (int c = t; c < NCOL * 16; c += 256) {
    int r = c >> 4, q = c & 15;
    int sq = q ^ (r & 15);
    *(short8*)&lbh[r * K + sq * 8] = *(const short8*)&Bhi[r * K + q * 8];
    *(short8*)&lbl[r * K + sq * 8] = *(const short8*)&Blo[r * K + q * 8];
  }
  __syncthreads();

  // ---- phase 3: pure LDS + MFMA, swapped operands ----
  f32x4 acc[2][NT] = {};
#pragma unroll
  for (int ks = 0; ks < 4; ++ks) {
    int chunk = ks * 4 + lk;
    bf16x8 bh[NT], bl[NT];
#pragma unroll
    for (int nt = 0; nt < NT; ++nt) {
      int r = nt * 16 + lm;
      int sq = chunk ^ lm;
      bh[nt] = *(const bf16x8*)&lbh[r * K + sq * 8];
      bl[nt] = *(const bf16x8*)&lbl[r * K + sq * 8];
    }
#pragma unroll
    for (int mt = 0; mt < 2; ++mt)
#pragma unroll
      for (int nt = 0; nt < NT; ++nt) {
        acc[mt][nt] = __builtin_amdgcn_mfma_f32_16x16x32_bf16(bh[nt], ah[mt][ks], acc[mt][nt], 0, 0, 0);
        acc[mt][nt] = __builtin_amdgcn_mfma_f32_16x16x32_bf16(bl[nt], ah[mt][ks], acc[mt][nt], 0, 0, 0);
        acc[mt][nt] = __builtin_amdgcn_mfma_f32_16x16x32_bf16(bh[nt], al[mt][ks], acc[mt][nt], 0, 0, 0);
      }
  }

  // ---- epilogue (transposed acc): row = m_base+mt*16+lm, cols = nt*16+lk*4+r
#pragma unroll
  for (int mt = 0; mt < 2; ++mt) {
    int row = m_base + mt * 16 + lm;
    if (row < M) {
      float dr = SCALE ? dinv[row] : 1.f;
#pragma unroll
      for (int nt = 0; nt < NT; ++nt) {
        int col0 = nt * 16 + lk * 4;
        float v0 = acc[mt][nt][0], v1 = acc[mt][nt][1];
        float v2 = acc[mt][nt][2], v3 = acc[mt][nt][3];
        if (SCALE) { v0 *= dr; v1 *= dr; v2 *= dr; v3 *= dr; }
        if (BIAS) {
          float4 bb = *(const float4*)&bias[col0];
          v0 += bb.x; v1 += bb.y; v2 += bb.z; v3 += bb.w;
        }
        if (OUT_BF16) {
          unsigned p0 = (unsigned)f2bf(v0) | ((unsigned)f2bf(v1) << 16);
          unsigned p1 = (unsigned)f2bf(v2) | ((unsigned)f2bf(v3) << 16);
          uint2 pk = make_uint2(p0, p1);
          *(uint2*)&((unsigned short*)Cout)[(size_t)row * NCOL + col0] = pk;
        } else {
          float4 pk = make_float4(v0, v1, v2, v3);
          *(float4*)&((float*)Cout)[(size_t)row * NCOL + col0] = pk;
        }
      }
    }
  }
}

// ------------------- aggregation: branchless padded CSR ------------------
// 4 nodes/block, 64 lanes/node: 4 edge groups x 16 feature lanes (16B).
// Row edge lists padded to x16 with zero-row index n -> NO clamps in loop.
// rows pre-scaled by dinv[src]; out = dinv_i*(sum + self) + bias, relu;
// output is fp32 (split to bf16 hi/lo happens in next gemm's A32 path).
__global__ __launch_bounds__(256) void k_agg(const unsigned short* __restrict__ t,
                      const int* __restrict__ row_off,
                      const unsigned short* __restrict__ edges,
                      const float* __restrict__ dinv, const float* __restrict__ bias,
                      float* __restrict__ gout, int n) {
  int wave = threadIdx.x >> 6;
  int lane = threadIdx.x & 63;
  int g = lane >> 4;
  int fl = lane & 15;          // features fl*8 .. fl*8+7
  int node = blockIdx.x * 4 + wave;
  if (node >= n) return;
  int2 ro = *(const int2*)&row_off[node];
  int e0 = ro.x, e1 = ro.y;    // padded range, multiple of 16

  // hoisted epilogue loads: overlap with gather chain
  float di = dinv[node];
  uint4 sv = *(const uint4*)&t[(size_t)node * 128 + fl * 8];
  float4 bb0 = *(const float4*)&bias[fl * 8];
  float4 bb1 = *(const float4*)&bias[fl * 8 + 4];

  f32x2 acc2[4] = {};
  for (int base = e0; base < e1; base += 16) {
    int s0 = edges[base + g];
    int s1 = edges[base + 4 + g];
    int s2 = edges[base + 8 + g];
    int s3 = edges[base + 12 + g];
    uint4 u0 = *(const uint4*)&t[(size_t)s0 * 128 + fl * 8];
    uint4 u1 = *(const uint4*)&t[(size_t)s1 * 128 + fl * 8];
    uint4 u2 = *(const uint4*)&t[(size_t)s2 * 128 + fl * 8];
    uint4 u3 = *(const uint4*)&t[(size_t)s3 * 128 + fl * 8];
    acc2[0] = pkadd(acc2[0], pkadd(pkadd(bfpair(u0.x), bfpair(u1.x)),
                                   pkadd(bfpair(u2.x), bfpair(u3.x))));
    acc2[1] = pkadd(acc2[1], pkadd(pkadd(bfpair(u0.y), bfpair(u1.y)),
                                   pkadd(bfpair(u2.y), bfpair(u3.y))));
    acc2[2] = pkadd(acc2[2], pkadd(pkadd(bfpair(u0.z), bfpair(u1.z)),
                                   pkadd(bfpair(u2.z), bfpair(u3.z))));
    acc2[3] = pkadd(acc2[3], pkadd(pkadd(bfpair(u0.w), bfpair(u1.w)),
                                   pkadd(bfpair(u2.w), bfpair(u3.w))));
  }
  float acc[8];
#pragma unroll
  for (int j = 0; j < 4; ++j) { acc[2 * j] = acc2[j].x; acc[2 * j + 1] = acc2[j].y; }
#pragma unroll
  for (int j = 0; j < 8; ++j) {
    acc[j] += __shfl_xor(acc[j], 16);
    acc[j] += __shfl_xor(acc[j], 32);
  }
  if (g == 0) {
    acc[0] += bf_lo(sv.x); acc[1] += bf_hi(sv.x);
    acc[2] += bf_lo(sv.y); acc[3] += bf_hi(sv.y);
    acc[4] += bf_lo(sv.z); acc[5] += bf_hi(sv.z);
    acc[6] += bf_lo(sv.w); acc[7] += bf_hi(sv.w);
    float bb[8] = {bb0.x, bb0.y, bb0.z, bb0.w, bb1.x, bb1.y, bb1.z, bb1.w};
    float4 o0, o1;
    o0.x = fmaxf(acc[0] * di + bb[0], 0.f);
    o0.y = fmaxf(acc[1] * di + bb[1], 0.f);
    o0.z = fmaxf(acc[2] * di + bb[2], 0.f);
    o0.w = fmaxf(acc[3] * di + bb[3], 0.f);
    o1.x = fmaxf(acc[4] * di + bb[4], 0.f);
    o1.y = fmaxf(acc[5] * di + bb[5], 0.f);
    o1.z = fmaxf(acc[6] * di + bb[6], 0.f);
    o1.w = fmaxf(acc[7] * di + bb[7], 0.f);
    *(float4*)&gout[(size_t)node * 128 + fl * 8] = o0;
    *(float4*)&gout[(size_t)node * 128 + fl * 8 + 4] = o1;
  }
}

extern "C" void kernel_launch(void* const* d_in, const int* in_sizes, int n_in,
                              void* d_out, int out_size, void* d_ws, size_t ws_size,
                              hipStream_t stream) {
  const float* x  = (const float*)d_in[0];
  const int*   ei = (const int*)d_in[1];
  const float* W1 = (const float*)d_in[2];
  const float* b1 = (const float*)d_in[3];
  const float* W2 = (const float*)d_in[4];
  const float* b2 = (const float*)d_in[5];
  const float* Wl = (const float*)d_in[6];
  const float* bl = (const float*)d_in[7];
  float* out = (float*)d_out;

  const int D = 128;
  int N = in_sizes[0] / D;
  int E = in_sizes[1] / 2;
  const int* src = ei;
  const int* dst = ei + E;

  uintptr_t ws = (uintptr_t)d_ws;
  auto take = [&](size_t bytes) {
    uintptr_t p = ws;
    ws += (bytes + 15) & ~(size_t)15;
    return p;
  };
  size_t Epad = (size_t)E + 16 * (size_t)N + 8;   // padded edges upper bound
  unsigned short* t_bf = (unsigned short*)take(((size_t)N + 1) * D * 2);  // + zero row
  float* xf            = (float*)take((size_t)N * D * 4);                 // fp32 agg out
  unsigned short* edges = (unsigned short*)take(Epad * 2);  // u16 src ids, padded
  int*   rank    = (int*)take((size_t)E * 4);
  int*   cnt     = (int*)take((size_t)N * sizeof(int));
  int*   row_off = (int*)take(((size_t)N + 1) * sizeof(int));
  float* dinv    = (float*)take((size_t)N * sizeof(float));
  int*   partial = (int*)take(256 * sizeof(int));
  unsigned short* b1h = (unsigned short*)take(128 * 128 * 2);
  unsigned short* b1l = (unsigned short*)take(128 * 128 * 2);
  unsigned short* b2h = (unsigned short*)take(128 * 128 * 2);
  unsigned short* b2l = (unsigned short*)take(128 * 128 * 2);
  unsigned short* blh = (unsigned short*)take(128 * 64 * 2);
  unsigned short* bll = (unsigned short*)take(128 * 64 * 2);

  int nb_n = (N + 255) / 256;   // 196 (fits single-block base reduce)
  int nb_e = (E + 255) / 256;
  int fill_q = (int)(Epad / 8); // uint4 fill count

  // ---- graph preprocessing + weight prep ----
  hipMemsetAsync(cnt, 0, (size_t)N * sizeof(int), stream);
  k_count_prepW<<<nb_e + 160 + 64, 256, 0, stream>>>(dst, E, nb_e, N, cnt, rank,
                                                     edges, fill_q,
                                                     W1, W2, Wl, b1h, b1l, b2h, b2l, blh, bll);
  k_scan1<<<nb_n, 256, 0, stream>>>(cnt, N, partial, dinv);
  k_scan3<<<nb_n, 256, 0, stream>>>(cnt, partial, nb_n, N, row_off);
  k_place<<<nb_e, 256, 0, stream>>>(src, dst, rank, row_off, E, edges);

  int gemm_blocks = (N + 127) / 128;
  int agg_blocks = (N + 3) / 4;

  // ---- layer 1 (A = fp32 x, split in-register; output pre-scaled by dinv) ----
  gemm3<8, true, false, true, true><<<gemm_blocks, 256, 0, stream>>>(
      x, nullptr, b1h, b1l, nullptr, dinv, t_bf, N);
  k_agg<<<agg_blocks, 256, 0, stream>>>(t_bf, row_off, edges, dinv, b1, xf, N);
  // ---- layer 2 (A = fp32 agg out, split in-register) ----
  gemm3<8, true, false, true, true><<<gemm_blocks, 256, 0, stream>>>(
      xf, nullptr, b2h, b2l, nullptr, dinv, t_bf, N);
  k_agg<<<agg_blocks, 256, 0, stream>>>(t_bf, row_off, edges, dinv, b2, xf, N);
  // ---- classifier ----
  gemm3<4, true, true, false, false><<<gemm_blocks, 256, 0, stream>>>(
      xf, nullptr, blh, bll, bl, nullptr, out, N);
}